// Round 4
// baseline (481.042 us; speedup 1.0000x reference)
//
#include <hip/hip_runtime.h>
#include <hip/hip_bf16.h>

using bf16 = __hip_bfloat16;
typedef __attribute__((ext_vector_type(8))) short bf16x8;
typedef __attribute__((ext_vector_type(8))) unsigned short u16x8;
typedef __attribute__((ext_vector_type(4))) float f32x4;

constexpr int BATCH = 4096;
constexpr int D_IN  = 1024;
constexpr int NEXP  = 16;
constexpr int EMB   = 256;
constexpr int H1    = 2048;
constexpr int H2    = 1024;
constexpr int OUTD  = 512;
constexpr int SLOTS = BATCH * 2;              // 8192 (token, expert) assignments
constexpr int SLOTS_PAD = SLOTS + 256;        // tile overrun pad
constexpr int MAX_TF = SLOTS / 256;           // 32 full 256-row tiles max
constexpr int MAX_TR = NEXP * 2;              // 32 remainder 128-row tiles max

// ---- workspace layout (bytes) ----
constexpr size_t WS_XB     = 0;                                    // bf16 x [4096][1024]
constexpr size_t WS_H1     = WS_XB     + (size_t)BATCH * D_IN * 2; // bf16 [SLOTS_PAD][2048]
constexpr size_t WS_H2     = WS_H1     + (size_t)SLOTS_PAD * H1 * 2;
constexpr size_t WS_OSL    = WS_H2     + (size_t)SLOTS_PAD * H2 * 2; // f32 [SLOTS_PAD][512]
constexpr size_t WS_TOPI   = WS_OSL    + (size_t)SLOTS_PAD * OUTD * 4;
constexpr size_t WS_GATES  = WS_TOPI   + (size_t)SLOTS * 4;
constexpr size_t WS_SLOTOF = WS_GATES  + (size_t)SLOTS * 4;
constexpr size_t WS_TOKL   = WS_SLOTOF + (size_t)SLOTS * 4;
constexpr size_t WS_CNT    = WS_TOKL   + (size_t)SLOTS_PAD * 4;    // counts16|offsets16|cursors16
constexpr size_t WS_TMAPF  = WS_CNT    + 64 * 4;                   // int2 [32]
constexpr size_t WS_TMAPR  = WS_TMAPF  + (size_t)MAX_TF * 8;       // int2 [32]
constexpr size_t WS_WT     = ((WS_TMAPR + (size_t)MAX_TR * 8) + 255) & ~(size_t)255;
// Wt: one layer at a time, max 16*2048*1024 bf16 = 64 MB

__device__ __forceinline__ unsigned short f2bf(float f) {
    bf16 h = __float2bfloat16(f);
    return __builtin_bit_cast(unsigned short, h);
}

__device__ __forceinline__ void gload16(const unsigned short* g, unsigned short* l) {
    __builtin_amdgcn_global_load_lds(
        (const __attribute__((address_space(1))) unsigned int*)g,
        (__attribute__((address_space(3))) unsigned int*)l, 16, 0, 0);
}

// ---------------- x -> bf16 ----------------
__global__ __launch_bounds__(256) void k_cvt_x(const float* __restrict__ x,
                                               unsigned short* __restrict__ xb) {
    int i = blockIdx.x * 256 + threadIdx.x;
    float4 v = reinterpret_cast<const float4*>(x)[i];
    ushort4 o;
    o.x = f2bf(v.x); o.y = f2bf(v.y); o.z = f2bf(v.z); o.w = f2bf(v.w);
    reinterpret_cast<ushort4*>(xb)[i] = o;
}

// ---------------- weight transpose+convert: W[e][k][n] f32 -> Wt[e][n][k] bf16 ----------------
__global__ __launch_bounds__(256) void k_wtrans(const float* __restrict__ W,
                                                unsigned short* __restrict__ Wt,
                                                int KD, int ND) {
    __shared__ float Tf[64][65];
    int e = blockIdx.z;
    int n0 = blockIdx.x * 64, k0 = blockIdx.y * 64;
    const float* Wb = W + ((size_t)e * KD + k0) * ND + n0;
    int t  = threadIdx.x;
    int kr = t >> 4, c4 = (t & 15) * 4;
#pragma unroll
    for (int i = 0; i < 4; i++) {
        float4 v = *reinterpret_cast<const float4*>(Wb + (size_t)(kr + i * 16) * ND + c4);
        Tf[kr + i * 16][c4 + 0] = v.x; Tf[kr + i * 16][c4 + 1] = v.y;
        Tf[kr + i * 16][c4 + 2] = v.z; Tf[kr + i * 16][c4 + 3] = v.w;
    }
    __syncthreads();
    unsigned short* Wtb = Wt + ((size_t)e * ND + n0) * KD + k0;
#pragma unroll
    for (int i = 0; i < 2; i++) {
        int idx = t + i * 256;
        int n = idx >> 3, ck = (idx & 7) * 8;
        u16x8 o;
#pragma unroll
        for (int j = 0; j < 8; j++) o[j] = f2bf(Tf[ck + j][n]);
        *reinterpret_cast<u16x8*>(Wtb + (size_t)n * KD + ck) = o;
    }
}

// ---------------- router GEMM: q = x @ Wr + br  (fp32, exactness matters) ----------------
__global__ __launch_bounds__(256) void k_router_gemm(const float* __restrict__ x,
                                                     const float* __restrict__ Wr,
                                                     const float* __restrict__ br,
                                                     float* __restrict__ qout) {
    __shared__ float As[64][17];
    __shared__ float Bs[16][68];
    int mb = blockIdx.x * 64, nb = blockIdx.y * 64;
    int t  = threadIdx.x;
    int tx = t & 15, ty = t >> 4;
    float acc[4][4] = {};
    int arow = t >> 2, ak = (t & 3) * 4;
    int bkr = t >> 4, bnc = (t & 15) * 4;
    for (int kt = 0; kt < D_IN; kt += 16) {
        float4 av = *reinterpret_cast<const float4*>(&x[(size_t)(mb + arow) * D_IN + kt + ak]);
        float4 bv = *reinterpret_cast<const float4*>(&Wr[(size_t)(kt + bkr) * EMB + nb + bnc]);
        As[arow][ak + 0] = av.x; As[arow][ak + 1] = av.y;
        As[arow][ak + 2] = av.z; As[arow][ak + 3] = av.w;
        Bs[bkr][bnc + 0] = bv.x; Bs[bkr][bnc + 1] = bv.y;
        Bs[bkr][bnc + 2] = bv.z; Bs[bkr][bnc + 3] = bv.w;
        __syncthreads();
#pragma unroll
        for (int k = 0; k < 16; k++) {
            float a[4], bb[4];
#pragma unroll
            for (int i = 0; i < 4; i++) a[i] = As[ty * 4 + i][k];
#pragma unroll
            for (int j = 0; j < 4; j++) bb[j] = Bs[k][tx * 4 + j];
#pragma unroll
            for (int i = 0; i < 4; i++)
#pragma unroll
                for (int j = 0; j < 4; j++) acc[i][j] = fmaf(a[i], bb[j], acc[i][j]);
        }
        __syncthreads();
    }
#pragma unroll
    for (int i = 0; i < 4; i++) {
        int row = mb + ty * 4 + i;
        float4 o;
        o.x = acc[i][0] + br[nb + tx * 4 + 0];
        o.y = acc[i][1] + br[nb + tx * 4 + 1];
        o.z = acc[i][2] + br[nb + tx * 4 + 2];
        o.w = acc[i][3] + br[nb + tx * 4 + 3];
        *reinterpret_cast<float4*>(&qout[(size_t)row * EMB + nb + tx * 4]) = o;
    }
}

// ---------------- distances, softmax, top-2 (one wave per example) ----------------
__global__ __launch_bounds__(256) void k_router_topk(const float* __restrict__ q,
                                                     const float* __restrict__ emb,
                                                     float* __restrict__ gp,
                                                     int* __restrict__ topi,
                                                     float* __restrict__ gates) {
    int b    = blockIdx.x * 4 + (threadIdx.x >> 6);
    int lane = threadIdx.x & 63;
    int e    = lane & 15;
    int seg  = (lane >> 4) * 64;
    const float* qr = q + (size_t)b * EMB + seg;
    const float* er = emb + (size_t)e * EMB + seg;
    float d2 = 0.f;
#pragma unroll 8
    for (int i = 0; i < 64; i++) { float d = qr[i] - er[i]; d2 = fmaf(d, d, d2); }
    d2 += __shfl_xor(d2, 16);
    d2 += __shfl_xor(d2, 32);
    float s = -d2;
    float m = s;
#pragma unroll
    for (int o = 1; o < 16; o <<= 1) m = fmaxf(m, __shfl_xor(m, o));
    float ex  = __expf(s - m);
    float sum = ex;
#pragma unroll
    for (int o = 1; o < 16; o <<= 1) sum += __shfl_xor(sum, o);
    if (lane < 16) gp[(size_t)b * NEXP + lane] = ex / sum;
    float v1 = s; int i1 = e;
#pragma unroll
    for (int o = 1; o < 16; o <<= 1) {
        float ov = __shfl_xor(v1, o); int oi = __shfl_xor(i1, o);
        if (ov > v1 || (ov == v1 && oi < i1)) { v1 = ov; i1 = oi; }
    }
    float s2 = (e == i1) ? -1e30f : s;
    float v2 = s2; int i2 = e;
#pragma unroll
    for (int o = 1; o < 16; o <<= 1) {
        float ov = __shfl_xor(v2, o); int oi = __shfl_xor(i2, o);
        if (ov > v2 || (ov == v2 && oi < i2)) { v2 = ov; i2 = oi; }
    }
    if (lane == 0) {
        topi[b * 2] = i1; topi[b * 2 + 1] = i2;
        float tv  = __expf(v2 - v1);
        float inv = 1.f / (1.f + tv);
        gates[b * 2] = inv; gates[b * 2 + 1] = tv * inv;
    }
}

// ---------------- routing bookkeeping ----------------
__global__ void k_zero(int* counts) { if (threadIdx.x < NEXP) counts[threadIdx.x] = 0; }

__global__ __launch_bounds__(256) void k_count(const int* __restrict__ topi, int* __restrict__ counts) {
    int i = blockIdx.x * 256 + threadIdx.x;
    atomicAdd(&counts[topi[i]], 1);
}

// Build offsets + two tilemaps: full 256-row tiles (unmasked fast path) and
// 128-row remainder tiles (masked path). Entries: (expert, base_row_in_expert).
__global__ void k_scan(const int* __restrict__ counts, int* __restrict__ offsets,
                       int* __restrict__ cursors, int2* __restrict__ tmapF,
                       int2* __restrict__ tmapR) {
    if (threadIdx.x != 0) return;
    int off = 0;
    for (int e = 0; e < NEXP; e++) {
        offsets[e] = off; cursors[e] = off;
        off += counts[e];
    }
    int ntF = 0, ntR = 0;
    for (int e = 0; e < NEXP; e++) {
        int c  = counts[e];
        int nF = c >> 8;
        for (int i = 0; i < nF; i++) tmapF[ntF++] = make_int2(e, i * 256);
        int base = nF * 256, rem = c - base;
        while (rem > 0) { tmapR[ntR++] = make_int2(e, base); base += 128; rem -= 128; }
    }
    for (; ntF < MAX_TF; ntF++) tmapF[ntF] = make_int2(-1, 0);
    for (; ntR < MAX_TR; ntR++) tmapR[ntR] = make_int2(-1, 0);
}

__global__ __launch_bounds__(256) void k_scatter(const int* __restrict__ topi, int* __restrict__ cursors,
                                                 int* __restrict__ toklist, int* __restrict__ slotof) {
    int i = blockIdx.x * 256 + threadIdx.x;
    int e = topi[i];
    int s = atomicAdd(&cursors[e], 1);
    toklist[s] = i >> 1;
    slotof[i]  = s;
}

// ---------------- grouped expert GEMM, 256x256 full-tile pass ----------------
// 512 threads = 8 waves (2M x 4N), per-wave 128x64 output (8x4 16x16x32 frags).
// BK=64, double-buffered 128KB LDS. Sync: STAGE(next) -> compute(cur) ->
// __syncthreads (vmcnt drain hidden under ~620cy of MFMA). Full tiles only:
// rows are guaranteed in-range -> no masking anywhere.
template <int KD, int ND, int MODE>
__global__ __launch_bounds__(512, 2) void k_gemm256(
    const unsigned short* __restrict__ Xin, const unsigned short* __restrict__ Wt,
    const float* __restrict__ bg, unsigned short* __restrict__ Hout,
    float* __restrict__ Oout, const int* __restrict__ offsets,
    const int* __restrict__ toklist, const int2* __restrict__ tmapF) {
    int2 tm = tmapF[blockIdx.y];
    int e = tm.x;
    if (e < 0) return;
    int base = tm.y;
    int off  = offsets[e];
    int n0   = blockIdx.x * 256;

    __shared__ __align__(16) unsigned short As[2][256 * 64];
    __shared__ __align__(16) unsigned short Bs[2][256 * 64];

    int t    = threadIdx.x;
    int lane = t & 63;
    int w    = t >> 6;
    int wm   = w >> 2;          // 0..1: M half
    int wn   = w & 3;           // 0..3: N quarter

    // staging: issue i covers row i*64 + (t>>3), chunk t&7 (16B), XOR-swizzled source
    int srow  = t >> 3;         // 0..63
    int chunk = t & 7;
    const unsigned short* asrc[4];
    const unsigned short* bsrc[4];
#pragma unroll
    for (int i = 0; i < 4; i++) {
        int row = i * 64 + srow;
        int swz = chunk ^ (row & 7);
        int g   = base + row;
        size_t arow = (MODE == 0) ? (size_t)toklist[off + g] : (size_t)(off + g);
        asrc[i] = Xin + arow * KD + swz * 8;
        bsrc[i] = Wt + ((size_t)e * ND + n0 + row) * KD + swz * 8;
    }

    auto STAGE = [&](int buf, int kt) {
#pragma unroll
        for (int i = 0; i < 4; i++) {
            gload16(asrc[i] + kt, &As[buf][(i * 64 + w * 8) * 64] + lane * 8);
            gload16(bsrc[i] + kt, &Bs[buf][(i * 64 + w * 8) * 64] + lane * 8);
        }
    };

    f32x4 acc[8][4];
#pragma unroll
    for (int mi = 0; mi < 8; mi++)
#pragma unroll
        for (int ni = 0; ni < 4; ni++) acc[mi][ni] = {0.f, 0.f, 0.f, 0.f};

    int lr  = lane & 15;
    int lkc = lane >> 4;

    constexpr int NT = KD / 64;
    STAGE(0, 0);
    __syncthreads();

    for (int tt = 0; tt < NT; tt++) {
        int cur = tt & 1;
        if (tt + 1 < NT) STAGE(cur ^ 1, (tt + 1) * 64);
        const char* Ab = (const char*)As[cur];
        const char* Bb = (const char*)Bs[cur];
#pragma unroll
        for (int ks = 0; ks < 2; ks++) {
            bf16x8 b[4];
#pragma unroll
            for (int ni = 0; ni < 4; ni++) {
                int row = wn * 64 + ni * 16 + lr;
                int c   = (lkc + ks * 4) ^ (row & 7);
                b[ni] = *reinterpret_cast<const bf16x8*>(Bb + row * 128 + c * 16);
            }
#pragma unroll
            for (int mq = 0; mq < 2; mq++) {
                bf16x8 a[4];
#pragma unroll
                for (int mi = 0; mi < 4; mi++) {
                    int row = wm * 128 + mq * 64 + mi * 16 + lr;
                    int c   = (lkc + ks * 4) ^ (row & 7);
                    a[mi] = *reinterpret_cast<const bf16x8*>(Ab + row * 128 + c * 16);
                }
#pragma unroll
                for (int mi = 0; mi < 4; mi++)
#pragma unroll
                    for (int ni = 0; ni < 4; ni++)
                        acc[mq * 4 + mi][ni] =
                            __builtin_amdgcn_mfma_f32_16x16x32_bf16(a[mi], b[ni], acc[mq * 4 + mi][ni], 0, 0, 0);
            }
        }
        if (tt + 1 < NT) __syncthreads();
    }

    // epilogue (full tile: no row masking). C/D map: col=lane&15, row=(lane>>4)*4+reg
    int rowbase = (lane >> 4) * 4;
#pragma unroll
    for (int ni = 0; ni < 4; ni++) {
        int col = n0 + wn * 64 + ni * 16 + lr;
        float bv = bg[(size_t)e * ND + col];
#pragma unroll
        for (int mi = 0; mi < 8; mi++) {
#pragma unroll
            for (int qi = 0; qi < 4; qi++) {
                int g = base + wm * 128 + mi * 16 + rowbase + qi;
                float v = acc[mi][ni][qi] + bv;
                if (MODE == 2) {
                    Oout[(size_t)(off + g) * ND + col] = v;
                } else {
                    v = fmaxf(v, 0.f);
                    Hout[(size_t)(off + g) * ND + col] = f2bf(v);
                }
            }
        }
    }
}

// ---------------- grouped expert GEMM, 128x128 remainder pass (masked) ----------------
template <int KD, int ND, int MODE>
__global__ __launch_bounds__(256, 2) void k_gemm128(
    const unsigned short* __restrict__ Xin, const unsigned short* __restrict__ Wt,
    const float* __restrict__ bg, unsigned short* __restrict__ Hout,
    float* __restrict__ Oout, const int* __restrict__ counts,
    const int* __restrict__ offsets, const int* __restrict__ toklist,
    const int2* __restrict__ tmapR) {
    int2 tm = tmapR[blockIdx.y];
    int e = tm.x;
    if (e < 0) return;
    int base = tm.y;
    int n_e  = counts[e];
    int off  = offsets[e];
    int n0   = blockIdx.x * 128;

    __shared__ __align__(16) unsigned short As[2][128 * 64];
    __shared__ __align__(16) unsigned short Bs[2][128 * 64];

    int t    = threadIdx.x;
    int lane = t & 63;
    int w    = t >> 6;
    int wr   = (w >> 1) * 64;
    int wc   = (w & 1) * 64;

    int srow = lane >> 3;
    int swz  = (lane & 7) ^ srow;
    const unsigned short* asrc[4];
    const unsigned short* bsrc[4];
#pragma unroll
    for (int i = 0; i < 4; i++) {
        int r = i * 32 + w * 8 + srow;
        int g = base + r;
        size_t arow;
        if (MODE == 0) {
            int gg = (g < n_e) ? g : (n_e - 1);
            arow = (size_t)toklist[off + gg];
        } else {
            arow = (size_t)(off + g);   // may bleed into pad; masked at store
        }
        asrc[i] = Xin + arow * KD + swz * 8;
        bsrc[i] = Wt + ((size_t)e * ND + n0 + r) * KD + swz * 8;
    }

    auto STAGE = [&](int buf, int kt) {
#pragma unroll
        for (int i = 0; i < 4; i++) {
            gload16(asrc[i] + kt, &As[buf][(i * 32 + w * 8) * 64] + lane * 8);
            gload16(bsrc[i] + kt, &Bs[buf][(i * 32 + w * 8) * 64] + lane * 8);
        }
    };

    f32x4 acc[4][4];
#pragma unroll
    for (int mi = 0; mi < 4; mi++)
#pragma unroll
        for (int ni = 0; ni < 4; ni++) acc[mi][ni] = {0.f, 0.f, 0.f, 0.f};

    int lr  = lane & 15;
    int lkc = lane >> 4;

    constexpr int NT = KD / 64;
    STAGE(0, 0);
    __syncthreads();

    for (int tt = 0; tt < NT; tt++) {
        int cur = tt & 1;
        if (tt + 1 < NT) STAGE(cur ^ 1, (tt + 1) * 64);
        const char* Ab = (const char*)As[cur];
        const char* Bb = (const char*)Bs[cur];
#pragma unroll
        for (int ks = 0; ks < 2; ks++) {
            bf16x8 a[4], b[4];
#pragma unroll
            for (int mi = 0; mi < 4; mi++) {
                int row = wr + mi * 16 + lr;
                int c   = (lkc + ks * 4) ^ (row & 7);
                a[mi] = *reinterpret_cast<const bf16x8*>(Ab + row * 128 + c * 16);
            }
#pragma unroll
            for (int ni = 0; ni < 4; ni++) {
                int row = wc + ni * 16 + lr;
                int c   = (lkc + ks * 4) ^ (row & 7);
                b[ni] = *reinterpret_cast<const bf16x8*>(Bb + row * 128 + c * 16);
            }
#pragma unroll
            for (int mi = 0; mi < 4; mi++)
#pragma unroll
                for (int ni = 0; ni < 4; ni++)
                    acc[mi][ni] = __builtin_amdgcn_mfma_f32_16x16x32_bf16(a[mi], b[ni], acc[mi][ni], 0, 0, 0);
        }
        if (tt + 1 < NT) __syncthreads();
    }

    int rowbase = (lane >> 4) * 4;
#pragma unroll
    for (int ni = 0; ni < 4; ni++) {
        int col = n0 + wc + ni * 16 + lr;
        float bv = bg[(size_t)e * ND + col];
#pragma unroll
        for (int mi = 0; mi < 4; mi++) {
#pragma unroll
            for (int qi = 0; qi < 4; qi++) {
                int g = base + wr + mi * 16 + rowbase + qi;
                if (g < n_e) {
                    float v = acc[mi][ni][qi] + bv;
                    if (MODE == 2) {
                        Oout[(size_t)(off + g) * ND + col] = v;
                    } else {
                        v = fmaxf(v, 0.f);
                        Hout[(size_t)(off + g) * ND + col] = f2bf(v);
                    }
                }
            }
        }
    }
}

// ---------------- final combine (deterministic 2-term sum) ----------------
__global__ __launch_bounds__(128) void k_combine(const float* __restrict__ osl,
                                                 const float* __restrict__ gates,
                                                 const int* __restrict__ slotof,
                                                 float* __restrict__ outf) {
    int b = blockIdx.x;
    int j = threadIdx.x;
    int s0 = slotof[b * 2], s1 = slotof[b * 2 + 1];
    float g0 = gates[b * 2], g1 = gates[b * 2 + 1];
    float4 o0 = reinterpret_cast<const float4*>(osl + (size_t)s0 * OUTD)[j];
    float4 o1 = reinterpret_cast<const float4*>(osl + (size_t)s1 * OUTD)[j];
    float4 r;
    r.x = g0 * o0.x + g1 * o1.x;
    r.y = g0 * o0.y + g1 * o1.y;
    r.z = g0 * o0.z + g1 * o1.z;
    r.w = g0 * o0.w + g1 * o1.w;
    reinterpret_cast<float4*>(outf + (size_t)b * OUTD)[j] = r;
}

extern "C" void kernel_launch(void* const* d_in, const int* in_sizes, int n_in,
                              void* d_out, int out_size, void* d_ws, size_t ws_size,
                              hipStream_t stream) {
    const float* x   = (const float*)d_in[0];
    const float* Wr  = (const float*)d_in[1];
    const float* br  = (const float*)d_in[2];
    const float* emb = (const float*)d_in[3];
    const float* W1  = (const float*)d_in[4];
    const float* b1  = (const float*)d_in[5];
    const float* W2  = (const float*)d_in[6];
    const float* b2  = (const float*)d_in[7];
    const float* W3  = (const float*)d_in[8];
    const float* b3  = (const float*)d_in[9];

    float* out_final = (float*)d_out;
    float* out_q     = out_final + (size_t)BATCH * OUTD;
    float* out_gp    = out_q + (size_t)BATCH * EMB;

    char* ws = (char*)d_ws;
    unsigned short* xb  = (unsigned short*)(ws + WS_XB);
    unsigned short* h1  = (unsigned short*)(ws + WS_H1);
    unsigned short* h2  = (unsigned short*)(ws + WS_H2);
    float* osl    = (float*)(ws + WS_OSL);
    int*   topi   = (int*)(ws + WS_TOPI);
    float* gates  = (float*)(ws + WS_GATES);
    int*   slotof = (int*)(ws + WS_SLOTOF);
    int*   toklist= (int*)(ws + WS_TOKL);
    int*   counts = (int*)(ws + WS_CNT);
    int*   offsets= counts + 16;
    int*   cursors= counts + 32;
    int2*  tmapF  = (int2*)(ws + WS_TMAPF);
    int2*  tmapR  = (int2*)(ws + WS_TMAPR);
    unsigned short* wt = (unsigned short*)(ws + WS_WT);

    k_cvt_x<<<BATCH * D_IN / 4 / 256, 256, 0, stream>>>(x, xb);
    k_router_gemm<<<dim3(BATCH / 64, EMB / 64), 256, 0, stream>>>(x, Wr, br, out_q);
    k_router_topk<<<BATCH / 4, 256, 0, stream>>>(out_q, emb, out_gp, topi, gates);
    k_zero<<<1, 64, 0, stream>>>(counts);
    k_count<<<SLOTS / 256, 256, 0, stream>>>(topi, counts);
    k_scan<<<1, 64, 0, stream>>>(counts, offsets, cursors, tmapF, tmapR);
    k_scatter<<<SLOTS / 256, 256, 0, stream>>>(topi, cursors, toklist, slotof);

    k_wtrans<<<dim3(H1 / 64, D_IN / 64, NEXP), 256, 0, stream>>>(W1, wt, D_IN, H1);
    k_gemm256<D_IN, H1, 0><<<dim3(H1 / 256, MAX_TF), 512, 0, stream>>>(
        xb, wt, b1, h1, nullptr, offsets, toklist, tmapF);
    k_gemm128<D_IN, H1, 0><<<dim3(H1 / 128, MAX_TR), 256, 0, stream>>>(
        xb, wt, b1, h1, nullptr, counts, offsets, toklist, tmapR);

    k_wtrans<<<dim3(H2 / 64, H1 / 64, NEXP), 256, 0, stream>>>(W2, wt, H1, H2);
    k_gemm256<H1, H2, 1><<<dim3(H2 / 256, MAX_TF), 512, 0, stream>>>(
        h1, wt, b2, h2, nullptr, offsets, toklist, tmapF);
    k_gemm128<H1, H2, 1><<<dim3(H2 / 128, MAX_TR), 256, 0, stream>>>(
        h1, wt, b2, h2, nullptr, counts, offsets, toklist, tmapR);

    k_wtrans<<<dim3(OUTD / 64, H2 / 64, NEXP), 256, 0, stream>>>(W3, wt, H2, OUTD);
    k_gemm256<H2, OUTD, 2><<<dim3(OUTD / 256, MAX_TF), 512, 0, stream>>>(
        h2, wt, b3, nullptr, osl, offsets, toklist, tmapF);
    k_gemm128<H2, OUTD, 2><<<dim3(OUTD / 128, MAX_TR), 256, 0, stream>>>(
        h2, wt, b3, nullptr, osl, counts, offsets, toklist, tmapR);

    k_combine<<<BATCH, 128, 0, stream>>>(osl, gates, slotof, out_final);
}

// Round 5
// 413.958 us; speedup vs baseline: 1.1621x; 1.1621x over previous
//
#include <hip/hip_runtime.h>
#include <hip/hip_bf16.h>

using bf16 = __hip_bfloat16;
typedef __attribute__((ext_vector_type(8))) short bf16x8;
typedef __attribute__((ext_vector_type(8))) unsigned short u16x8;
typedef __attribute__((ext_vector_type(4))) float f32x4;

constexpr int BATCH = 4096;
constexpr int D_IN  = 1024;
constexpr int NEXP  = 16;
constexpr int EMB   = 256;
constexpr int H1    = 2048;
constexpr int H2    = 1024;
constexpr int OUTD  = 512;
constexpr int SLOTS = BATCH * 2;              // 8192 (token, expert) assignments
constexpr int SLOTS_PAD = SLOTS + 256;        // 256-row tile overrun pad
constexpr int MAX_T = SLOTS / 256 + NEXP;     // 48: sum ceil(n_e/256) bound
constexpr int K3    = 3 * D_IN;               // router bf16x3 extended K

// ---- workspace layout (bytes) ----
constexpr size_t WS_XB     = 0;                                    // bf16 xhi [4096][1024]
constexpr size_t WS_XLO    = WS_XB     + (size_t)BATCH * D_IN * 2; // bf16 xlo [4096][1024]
constexpr size_t WS_H1     = WS_XLO    + (size_t)BATCH * D_IN * 2; // bf16 [SLOTS_PAD][2048]
constexpr size_t WS_H2     = WS_H1     + (size_t)SLOTS_PAD * H1 * 2;
constexpr size_t WS_OSL    = WS_H2     + (size_t)SLOTS_PAD * H2 * 2; // f32 [SLOTS_PAD][512]
constexpr size_t WS_TOPI   = WS_OSL    + (size_t)SLOTS_PAD * OUTD * 4;
constexpr size_t WS_GATES  = WS_TOPI   + (size_t)SLOTS * 4;
constexpr size_t WS_SLOTOF = WS_GATES  + (size_t)SLOTS * 4;
constexpr size_t WS_TOKL   = WS_SLOTOF + (size_t)SLOTS * 4;
constexpr size_t WS_CNT    = WS_TOKL   + (size_t)SLOTS_PAD * 4;    // counts16|offsets16|cursors16
constexpr size_t WS_TMAP   = WS_CNT    + 64 * 4;                   // int2 [48]
constexpr size_t WS_WR3    = ((WS_TMAP + (size_t)MAX_T * 8) + 255) & ~(size_t)255;
constexpr size_t WS_WT     = ((WS_WR3 + (size_t)EMB * K3 * 2) + 255) & ~(size_t)255;
// Wt: one layer at a time, max 16*2048*1024 bf16 = 64 MB

__device__ __forceinline__ unsigned short f2bf(float f) {
    bf16 h = __float2bfloat16(f);
    return __builtin_bit_cast(unsigned short, h);
}
__device__ __forceinline__ float bf2f(unsigned short h) {
    return __builtin_bit_cast(float, (unsigned)h << 16);
}

__device__ __forceinline__ void gload16(const unsigned short* g, unsigned short* l) {
    __builtin_amdgcn_global_load_lds(
        (const __attribute__((address_space(1))) unsigned int*)g,
        (__attribute__((address_space(3))) unsigned int*)l, 16, 0, 0);
}

// ---------------- x -> bf16 hi + lo residual ----------------
__global__ __launch_bounds__(256) void k_cvt_x(const float* __restrict__ x,
                                               unsigned short* __restrict__ xhi,
                                               unsigned short* __restrict__ xlo) {
    int i = blockIdx.x * 256 + threadIdx.x;
    float4 v = reinterpret_cast<const float4*>(x)[i];
    ushort4 h, l;
    h.x = f2bf(v.x); h.y = f2bf(v.y); h.z = f2bf(v.z); h.w = f2bf(v.w);
    l.x = f2bf(v.x - bf2f(h.x)); l.y = f2bf(v.y - bf2f(h.y));
    l.z = f2bf(v.z - bf2f(h.z)); l.w = f2bf(v.w - bf2f(h.w));
    reinterpret_cast<ushort4*>(xhi)[i] = h;
    reinterpret_cast<ushort4*>(xlo)[i] = l;
}

// ---------------- Wr[k][n] f32 -> Wrt3[n][3072] bf16 = [Whi | Whi | Wlo] ----------------
__global__ __launch_bounds__(256) void k_wr3(const float* __restrict__ Wr,
                                             unsigned short* __restrict__ Wrt3) {
    __shared__ float Tf[64][65];
    int n0 = blockIdx.x * 64, k0 = blockIdx.y * 64;
    const float* Wb = Wr + (size_t)k0 * EMB + n0;
    int t  = threadIdx.x;
    int kr = t >> 4, c4 = (t & 15) * 4;
#pragma unroll
    for (int i = 0; i < 4; i++) {
        float4 v = *reinterpret_cast<const float4*>(Wb + (size_t)(kr + i * 16) * EMB + c4);
        Tf[kr + i * 16][c4 + 0] = v.x; Tf[kr + i * 16][c4 + 1] = v.y;
        Tf[kr + i * 16][c4 + 2] = v.z; Tf[kr + i * 16][c4 + 3] = v.w;
    }
    __syncthreads();
#pragma unroll
    for (int i = 0; i < 2; i++) {
        int idx = t + i * 256;
        int n = idx >> 3, ck = (idx & 7) * 8;
        u16x8 hi, lo;
#pragma unroll
        for (int j = 0; j < 8; j++) {
            float w = Tf[ck + j][n];
            unsigned short h = f2bf(w);
            hi[j] = h; lo[j] = f2bf(w - bf2f(h));
        }
        unsigned short* dst = Wrt3 + (size_t)(n0 + n) * K3 + k0 + ck;
        *reinterpret_cast<u16x8*>(dst)            = hi;
        *reinterpret_cast<u16x8*>(dst + D_IN)     = hi;
        *reinterpret_cast<u16x8*>(dst + 2 * D_IN) = lo;
    }
}

// ---------------- weight transpose+convert: W[e][k][n] f32 -> Wt[e][n][k] bf16 ----------------
__global__ __launch_bounds__(256) void k_wtrans(const float* __restrict__ W,
                                                unsigned short* __restrict__ Wt,
                                                int KD, int ND) {
    __shared__ float Tf[64][65];
    int e = blockIdx.z;
    int n0 = blockIdx.x * 64, k0 = blockIdx.y * 64;
    const float* Wb = W + ((size_t)e * KD + k0) * ND + n0;
    int t  = threadIdx.x;
    int kr = t >> 4, c4 = (t & 15) * 4;
#pragma unroll
    for (int i = 0; i < 4; i++) {
        float4 v = *reinterpret_cast<const float4*>(Wb + (size_t)(kr + i * 16) * ND + c4);
        Tf[kr + i * 16][c4 + 0] = v.x; Tf[kr + i * 16][c4 + 1] = v.y;
        Tf[kr + i * 16][c4 + 2] = v.z; Tf[kr + i * 16][c4 + 3] = v.w;
    }
    __syncthreads();
    unsigned short* Wtb = Wt + ((size_t)e * ND + n0) * KD + k0;
#pragma unroll
    for (int i = 0; i < 2; i++) {
        int idx = t + i * 256;
        int n = idx >> 3, ck = (idx & 7) * 8;
        u16x8 o;
#pragma unroll
        for (int j = 0; j < 8; j++) o[j] = f2bf(Tf[ck + j][n]);
        *reinterpret_cast<u16x8*>(Wtb + (size_t)n * KD + ck) = o;
    }
}

// ---------------- router GEMM via bf16x3: q = x@Wr + br in ~fp32 accuracy ----------------
// One bf16 MFMA GEMM with K=3072: A_ext=[xhi|xlo|xhi], B_ext=[Whi|Whi|Wlo].
// 64x64 tile, 256 thr / 4 waves (2x2), BK=64 double-buffered, proven
// swizzle+gload16 staging. Grid (EMB/64, BATCH/64) = 256 blocks.
__global__ __launch_bounds__(256) void k_router3(const unsigned short* __restrict__ xhi,
                                                 const unsigned short* __restrict__ xlo,
                                                 const unsigned short* __restrict__ wrt3,
                                                 const float* __restrict__ br,
                                                 float* __restrict__ qout) {
    int nb = blockIdx.x * 64;
    int mb = blockIdx.y * 64;

    __shared__ __align__(16) unsigned short As[2][64 * 64];
    __shared__ __align__(16) unsigned short Bs[2][64 * 64];

    int t    = threadIdx.x;
    int lane = t & 63;
    int w    = t >> 6;
    int wr   = (w >> 1) * 32;
    int wc   = (w & 1) * 32;

    int srow = t >> 3;                       // 0..31 per issue
    int swz  = (t & 7) ^ (srow & 7);
    size_t aoff[2], boff[2];
#pragma unroll
    for (int i = 0; i < 2; i++) {
        int row = i * 32 + srow;
        aoff[i] = (size_t)(mb + row) * D_IN + swz * 8;
        boff[i] = (size_t)(nb + row) * K3 + swz * 8;
    }

    auto STAGE = [&](int buf, int tts) {
        const unsigned short* abase = (tts >= 16 && tts < 32) ? xlo : xhi;
        int kk = (tts & 15) * 64;
#pragma unroll
        for (int i = 0; i < 2; i++) {
            gload16(abase + aoff[i] + kk, &As[buf][(i * 32 + w * 8) * 64] + lane * 8);
            gload16(wrt3 + boff[i] + tts * 64, &Bs[buf][(i * 32 + w * 8) * 64] + lane * 8);
        }
    };

    f32x4 acc[2][2];
#pragma unroll
    for (int mi = 0; mi < 2; mi++)
#pragma unroll
        for (int ni = 0; ni < 2; ni++) acc[mi][ni] = {0.f, 0.f, 0.f, 0.f};

    int lr  = lane & 15;
    int lkc = lane >> 4;

    constexpr int NT = K3 / 64;   // 48
    STAGE(0, 0);
    __syncthreads();

    for (int tt = 0; tt < NT; tt++) {
        int cur = tt & 1;
        if (tt + 1 < NT) STAGE(cur ^ 1, tt + 1);
        const char* Ab = (const char*)As[cur];
        const char* Bb = (const char*)Bs[cur];
#pragma unroll
        for (int ks = 0; ks < 2; ks++) {
            bf16x8 a[2], b[2];
#pragma unroll
            for (int mi = 0; mi < 2; mi++) {
                int row = wr + mi * 16 + lr;
                int c   = (lkc + ks * 4) ^ (row & 7);
                a[mi] = *reinterpret_cast<const bf16x8*>(Ab + row * 128 + c * 16);
            }
#pragma unroll
            for (int ni = 0; ni < 2; ni++) {
                int row = wc + ni * 16 + lr;
                int c   = (lkc + ks * 4) ^ (row & 7);
                b[ni] = *reinterpret_cast<const bf16x8*>(Bb + row * 128 + c * 16);
            }
#pragma unroll
            for (int mi = 0; mi < 2; mi++)
#pragma unroll
                for (int ni = 0; ni < 2; ni++)
                    acc[mi][ni] = __builtin_amdgcn_mfma_f32_16x16x32_bf16(a[mi], b[ni], acc[mi][ni], 0, 0, 0);
        }
        if (tt + 1 < NT) __syncthreads();
    }

    int rowbase = (lane >> 4) * 4;
#pragma unroll
    for (int ni = 0; ni < 2; ni++) {
        int col = nb + wc + ni * 16 + lr;
        float bv = br[col];
#pragma unroll
        for (int mi = 0; mi < 2; mi++) {
#pragma unroll
            for (int qi = 0; qi < 4; qi++) {
                int row = mb + wr + mi * 16 + rowbase + qi;
                qout[(size_t)row * EMB + col] = acc[mi][ni][qi] + bv;
            }
        }
    }
}

// ---------------- distances, softmax, top-2 (one wave per example) ----------------
__global__ __launch_bounds__(256) void k_router_topk(const float* __restrict__ q,
                                                     const float* __restrict__ emb,
                                                     float* __restrict__ gp,
                                                     int* __restrict__ topi,
                                                     float* __restrict__ gates) {
    int b    = blockIdx.x * 4 + (threadIdx.x >> 6);
    int lane = threadIdx.x & 63;
    int e    = lane & 15;
    int seg  = (lane >> 4) * 64;
    const float* qr = q + (size_t)b * EMB + seg;
    const float* er = emb + (size_t)e * EMB + seg;
    float d2 = 0.f;
#pragma unroll 8
    for (int i = 0; i < 64; i++) { float d = qr[i] - er[i]; d2 = fmaf(d, d, d2); }
    d2 += __shfl_xor(d2, 16);
    d2 += __shfl_xor(d2, 32);
    float s = -d2;
    float m = s;
#pragma unroll
    for (int o = 1; o < 16; o <<= 1) m = fmaxf(m, __shfl_xor(m, o));
    float ex  = __expf(s - m);
    float sum = ex;
#pragma unroll
    for (int o = 1; o < 16; o <<= 1) sum += __shfl_xor(sum, o);
    if (lane < 16) gp[(size_t)b * NEXP + lane] = ex / sum;
    float v1 = s; int i1 = e;
#pragma unroll
    for (int o = 1; o < 16; o <<= 1) {
        float ov = __shfl_xor(v1, o); int oi = __shfl_xor(i1, o);
        if (ov > v1 || (ov == v1 && oi < i1)) { v1 = ov; i1 = oi; }
    }
    float s2 = (e == i1) ? -1e30f : s;
    float v2 = s2; int i2 = e;
#pragma unroll
    for (int o = 1; o < 16; o <<= 1) {
        float ov = __shfl_xor(v2, o); int oi = __shfl_xor(i2, o);
        if (ov > v2 || (ov == v2 && oi < i2)) { v2 = ov; i2 = oi; }
    }
    if (lane == 0) {
        topi[b * 2] = i1; topi[b * 2 + 1] = i2;
        float tv  = __expf(v2 - v1);
        float inv = 1.f / (1.f + tv);
        gates[b * 2] = inv; gates[b * 2 + 1] = tv * inv;
    }
}

// ---------------- routing bookkeeping ----------------
__global__ void k_zero(int* counts) { if (threadIdx.x < NEXP) counts[threadIdx.x] = 0; }

__global__ __launch_bounds__(256) void k_count(const int* __restrict__ topi, int* __restrict__ counts) {
    int i = blockIdx.x * 256 + threadIdx.x;
    atomicAdd(&counts[topi[i]], 1);
}

// offsets + single tilemap at 256-row granularity (masked tiles handle tails)
__global__ void k_scan(const int* __restrict__ counts, int* __restrict__ offsets,
                       int* __restrict__ cursors, int2* __restrict__ tmap) {
    if (threadIdx.x != 0) return;
    int off = 0;
    for (int e = 0; e < NEXP; e++) {
        offsets[e] = off; cursors[e] = off;
        off += counts[e];
    }
    int nt = 0;
    for (int e = 0; e < NEXP; e++) {
        int c = counts[e];
        for (int base = 0; base < c; base += 256) tmap[nt++] = make_int2(e, base);
    }
    for (; nt < MAX_T; nt++) tmap[nt] = make_int2(-1, 0);
}

__global__ __launch_bounds__(256) void k_scatter(const int* __restrict__ topi, int* __restrict__ cursors,
                                                 int* __restrict__ toklist, int* __restrict__ slotof) {
    int i = blockIdx.x * 256 + threadIdx.x;
    int e = topi[i];
    int s = atomicAdd(&cursors[e], 1);
    toklist[s] = i >> 1;
    slotof[i]  = s;
}

// ---------------- grouped expert GEMM, single masked 256x256 pass ----------------
// 512 thr = 8 waves (2M x 4N), per-wave 128x64 out (8x4 16x16x32 frags), BK=64,
// double-buffered 128KB LDS, swizzled gload16 staging, 2-phase schedule.
// __launch_bounds__(512, 1): acc needs 128 VGPR alone; (512,2) caps at 128 -> spills.
// MODE 0: gather x rows, relu -> bf16 h    (L1)
// MODE 1: contiguous h in, relu -> bf16 h  (L2)
// MODE 2: contiguous h in, fp32 out + bias (L3)
template <int KD, int ND, int MODE>
__global__ __launch_bounds__(512, 1) void k_gemm256(
    const unsigned short* __restrict__ Xin, const unsigned short* __restrict__ Wt,
    const float* __restrict__ bg, unsigned short* __restrict__ Hout,
    float* __restrict__ Oout, const int* __restrict__ counts,
    const int* __restrict__ offsets, const int* __restrict__ toklist,
    const int2* __restrict__ tmap) {
    int2 tm = tmap[blockIdx.y];
    int e = tm.x;
    if (e < 0) return;
    int base = tm.y;
    int n_e  = counts[e];
    int off  = offsets[e];
    int n0   = blockIdx.x * 256;

    __shared__ __align__(16) unsigned short As[2][256 * 64];
    __shared__ __align__(16) unsigned short Bs[2][256 * 64];

    int t    = threadIdx.x;
    int lane = t & 63;
    int w    = t >> 6;
    int wm   = w >> 2;          // 0..1: M half
    int wn   = w & 3;           // 0..3: N quarter

    // staging: issue i covers row i*64 + (t>>3), chunk t&7 (16B), XOR-swizzled source
    int srow  = t >> 3;         // 0..63
    int chunk = t & 7;
    const unsigned short* asrc[4];
    const unsigned short* bsrc[4];
#pragma unroll
    for (int i = 0; i < 4; i++) {
        int row = i * 64 + srow;
        int swz = chunk ^ (row & 7);
        int g   = base + row;
        size_t arow;
        if (MODE == 0) {
            int gg = (g < n_e) ? g : (n_e - 1);
            arow = (size_t)toklist[off + gg];
        } else {
            arow = (size_t)(off + g);   // may bleed into pad; masked at store
        }
        asrc[i] = Xin + arow * KD + swz * 8;
        bsrc[i] = Wt + ((size_t)e * ND + n0 + row) * KD + swz * 8;
    }

    auto STAGE = [&](int buf, int kt) {
#pragma unroll
        for (int i = 0; i < 4; i++) {
            gload16(asrc[i] + kt, &As[buf][(i * 64 + w * 8) * 64] + lane * 8);
            gload16(bsrc[i] + kt, &Bs[buf][(i * 64 + w * 8) * 64] + lane * 8);
        }
    };

    f32x4 acc[8][4];
#pragma unroll
    for (int mi = 0; mi < 8; mi++)
#pragma unroll
        for (int ni = 0; ni < 4; ni++) acc[mi][ni] = {0.f, 0.f, 0.f, 0.f};

    int lr  = lane & 15;
    int lkc = lane >> 4;

    constexpr int NT = KD / 64;
    STAGE(0, 0);
    __syncthreads();

    for (int tt = 0; tt < NT; tt++) {
        int cur = tt & 1;
        if (tt + 1 < NT) STAGE(cur ^ 1, (tt + 1) * 64);
        const char* Ab = (const char*)As[cur];
        const char* Bb = (const char*)Bs[cur];
#pragma unroll
        for (int ks = 0; ks < 2; ks++) {
            bf16x8 b[4];
#pragma unroll
            for (int ni = 0; ni < 4; ni++) {
                int row = wn * 64 + ni * 16 + lr;
                int c   = (lkc + ks * 4) ^ (row & 7);
                b[ni] = *reinterpret_cast<const bf16x8*>(Bb + row * 128 + c * 16);
            }
#pragma unroll
            for (int mq = 0; mq < 2; mq++) {
                bf16x8 a[4];
#pragma unroll
                for (int mi = 0; mi < 4; mi++) {
                    int row = wm * 128 + mq * 64 + mi * 16 + lr;
                    int c   = (lkc + ks * 4) ^ (row & 7);
                    a[mi] = *reinterpret_cast<const bf16x8*>(Ab + row * 128 + c * 16);
                }
#pragma unroll
                for (int mi = 0; mi < 4; mi++)
#pragma unroll
                    for (int ni = 0; ni < 4; ni++)
                        acc[mq * 4 + mi][ni] =
                            __builtin_amdgcn_mfma_f32_16x16x32_bf16(a[mi], b[ni], acc[mq * 4 + mi][ni], 0, 0, 0);
            }
        }
        if (tt + 1 < NT) __syncthreads();
    }

    // epilogue (masked). C/D map: col=lane&15, row=(lane>>4)*4+reg
    int rowbase = (lane >> 4) * 4;
#pragma unroll
    for (int ni = 0; ni < 4; ni++) {
        int col = n0 + wn * 64 + ni * 16 + lr;
        float bv = bg[(size_t)e * ND + col];
#pragma unroll
        for (int mi = 0; mi < 8; mi++) {
#pragma unroll
            for (int qi = 0; qi < 4; qi++) {
                int g = base + wm * 128 + mi * 16 + rowbase + qi;
                if (g < n_e) {
                    float v = acc[mi][ni][qi] + bv;
                    if (MODE == 2) {
                        Oout[(size_t)(off + g) * ND + col] = v;
                    } else {
                        v = fmaxf(v, 0.f);
                        Hout[(size_t)(off + g) * ND + col] = f2bf(v);
                    }
                }
            }
        }
    }
}

// ---------------- final combine (deterministic 2-term sum) ----------------
__global__ __launch_bounds__(128) void k_combine(const float* __restrict__ osl,
                                                 const float* __restrict__ gates,
                                                 const int* __restrict__ slotof,
                                                 float* __restrict__ outf) {
    int b = blockIdx.x;
    int j = threadIdx.x;
    int s0 = slotof[b * 2], s1 = slotof[b * 2 + 1];
    float g0 = gates[b * 2], g1 = gates[b * 2 + 1];
    float4 o0 = reinterpret_cast<const float4*>(osl + (size_t)s0 * OUTD)[j];
    float4 o1 = reinterpret_cast<const float4*>(osl + (size_t)s1 * OUTD)[j];
    float4 r;
    r.x = g0 * o0.x + g1 * o1.x;
    r.y = g0 * o0.y + g1 * o1.y;
    r.z = g0 * o0.z + g1 * o1.z;
    r.w = g0 * o0.w + g1 * o1.w;
    reinterpret_cast<float4*>(outf + (size_t)b * OUTD)[j] = r;
}

extern "C" void kernel_launch(void* const* d_in, const int* in_sizes, int n_in,
                              void* d_out, int out_size, void* d_ws, size_t ws_size,
                              hipStream_t stream) {
    const float* x   = (const float*)d_in[0];
    const float* Wr  = (const float*)d_in[1];
    const float* br  = (const float*)d_in[2];
    const float* emb = (const float*)d_in[3];
    const float* W1  = (const float*)d_in[4];
    const float* b1  = (const float*)d_in[5];
    const float* W2  = (const float*)d_in[6];
    const float* b2  = (const float*)d_in[7];
    const float* W3  = (const float*)d_in[8];
    const float* b3  = (const float*)d_in[9];

    float* out_final = (float*)d_out;
    float* out_q     = out_final + (size_t)BATCH * OUTD;
    float* out_gp    = out_q + (size_t)BATCH * EMB;

    char* ws = (char*)d_ws;
    unsigned short* xb  = (unsigned short*)(ws + WS_XB);
    unsigned short* xlo = (unsigned short*)(ws + WS_XLO);
    unsigned short* h1  = (unsigned short*)(ws + WS_H1);
    unsigned short* h2  = (unsigned short*)(ws + WS_H2);
    float* osl    = (float*)(ws + WS_OSL);
    int*   topi   = (int*)(ws + WS_TOPI);
    float* gates  = (float*)(ws + WS_GATES);
    int*   slotof = (int*)(ws + WS_SLOTOF);
    int*   toklist= (int*)(ws + WS_TOKL);
    int*   counts = (int*)(ws + WS_CNT);
    int*   offsets= counts + 16;
    int*   cursors= counts + 32;
    int2*  tmap   = (int2*)(ws + WS_TMAP);
    unsigned short* wrt3 = (unsigned short*)(ws + WS_WR3);
    unsigned short* wt   = (unsigned short*)(ws + WS_WT);

    k_cvt_x<<<BATCH * D_IN / 4 / 256, 256, 0, stream>>>(x, xb, xlo);
    k_wr3<<<dim3(EMB / 64, D_IN / 64), 256, 0, stream>>>(Wr, wrt3);
    k_router3<<<dim3(EMB / 64, BATCH / 64), 256, 0, stream>>>(xb, xlo, wrt3, br, out_q);
    k_router_topk<<<BATCH / 4, 256, 0, stream>>>(out_q, emb, out_gp, topi, gates);
    k_zero<<<1, 64, 0, stream>>>(counts);
    k_count<<<SLOTS / 256, 256, 0, stream>>>(topi, counts);
    k_scan<<<1, 64, 0, stream>>>(counts, offsets, cursors, tmap);
    k_scatter<<<SLOTS / 256, 256, 0, stream>>>(topi, cursors, toklist, slotof);

    k_wtrans<<<dim3(H1 / 64, D_IN / 64, NEXP), 256, 0, stream>>>(W1, wt, D_IN, H1);
    k_gemm256<D_IN, H1, 0><<<dim3(H1 / 256, MAX_T), 512, 0, stream>>>(
        xb, wt, b1, h1, nullptr, counts, offsets, toklist, tmap);

    k_wtrans<<<dim3(H2 / 64, H1 / 64, NEXP), 256, 0, stream>>>(W2, wt, H1, H2);
    k_gemm256<H1, H2, 1><<<dim3(H2 / 256, MAX_T), 512, 0, stream>>>(
        h1, wt, b2, h2, nullptr, counts, offsets, toklist, tmap);

    k_wtrans<<<dim3(OUTD / 64, H2 / 64, NEXP), 256, 0, stream>>>(W3, wt, H2, OUTD);
    k_gemm256<H2, OUTD, 2><<<dim3(OUTD / 256, MAX_T), 512, 0, stream>>>(
        h2, wt, b3, nullptr, osl, counts, offsets, toklist, tmap);

    k_combine<<<BATCH, 128, 0, stream>>>(osl, gates, slotof, out_final);
}